// Round 1
// baseline (856.771 us; speedup 1.0000x reference)
//
#include <hip/hip_runtime.h>
#include <hip/hip_bf16.h>
#include <hip/hip_fp16.h>

// Nystromformer layer: b=4, n=4096, dim=512, heads=8, dim_head=64, m=256, pinv_iters=6
#define B_ 4
#define H_ 8
#define N_ 4096
#define DH_ 64
#define D_ 512
#define M_ 256
#define BH_ 32
#define NT_ 16384

typedef unsigned short u16;
using sh8 = __attribute__((ext_vector_type(8))) short;
using sh4 = __attribute__((ext_vector_type(4))) short;
using f4  = __attribute__((ext_vector_type(4))) float;

__device__ __forceinline__ float bf2f(u16 u){ return __uint_as_float(((unsigned)u)<<16); }
__device__ __forceinline__ u16 f2bf(float f){
  unsigned u = __float_as_uint(f);
  u += 0x7fffu + ((u>>16)&1u);
  return (u16)(u>>16);
}

// ---------------- LayerNorm: x f32 (16384x512) -> h bf16 ----------------
__global__ __launch_bounds__(256) void ln_kernel(const float* __restrict__ x,
    const float* __restrict__ w, const float* __restrict__ b, u16* __restrict__ h){
  int row = blockIdx.x;
  const float2* xr = (const float2*)(x + (size_t)row*D_);
  int t = threadIdx.x;
  float2 v = xr[t];
  float s = v.x+v.y, ss = v.x*v.x+v.y*v.y;
  #pragma unroll
  for (int o=32;o;o>>=1){ s += __shfl_xor(s,o); ss += __shfl_xor(ss,o); }
  __shared__ float sb[4], sb2[4];
  if ((t&63)==0){ sb[t>>6]=s; sb2[t>>6]=ss; }
  __syncthreads();
  float ts  = sb[0]+sb[1]+sb[2]+sb[3];
  float tss = sb2[0]+sb2[1]+sb2[2]+sb2[3];
  float mean = ts*(1.f/D_);
  float var  = tss*(1.f/D_) - mean*mean;
  float rstd = rsqrtf(var+1e-5f);
  int c = 2*t;
  float o0 = (v.x-mean)*rstd*w[c]   + b[c];
  float o1 = (v.y-mean)*rstd*w[c+1] + b[c+1];
  u16* hr = h + (size_t)row*D_;
  hr[c] = f2bf(o0); hr[c+1] = f2bf(o1);
}

// ---------------- transpose-cast f32 [K][N] -> bf16 [N][K] ----------------
__global__ void castT_kernel(const float* __restrict__ in, u16* __restrict__ out, int K, int N){
  int idx = blockIdx.x*256 + threadIdx.x;
  if (idx < K*N){ int k = idx/N, n = idx - k*N; out[(size_t)n*K + k] = f2bf(in[idx]); }
}

// ---------------- QKV GEMM: h(16384x512) @ wqkvT(1536x512)^T, scatter q,k,v ----------------
__global__ __launch_bounds__(256) void gemm_qkv(const u16* __restrict__ A,
    const u16* __restrict__ Bt, u16* __restrict__ q, u16* __restrict__ k, u16* __restrict__ v){
  __shared__ short As[128*72], Bs[128*72];
  int r0 = blockIdx.x*128, c0 = blockIdx.y*128;
  int tid = threadIdx.x, lane = tid&63, w = tid>>6;
  int wr = w>>1, wc = w&1;
  f4 acc[4][4];
  #pragma unroll
  for (int i=0;i<4;i++){
    #pragma unroll
    for (int j=0;j<4;j++) acc[i][j]=0;
  }
  for (int kt=0;kt<8;kt++){
    __syncthreads();
    #pragma unroll
    for (int i=0;i<4;i++){
      int c = i*256+tid, row = c>>3, kg = c&7;
      *(sh8*)&As[row*72+kg*8] = *(const sh8*)(A + (size_t)(r0+row)*512 + kt*64 + kg*8);
      *(sh8*)&Bs[row*72+kg*8] = *(const sh8*)(Bt + (size_t)(c0+row)*512 + kt*64 + kg*8);
    }
    __syncthreads();
    #pragma unroll
    for (int kc=0;kc<2;kc++){
      sh8 a[4], bq[4];
      #pragma unroll
      for (int fr=0;fr<4;fr++) a[fr]  = *(const sh8*)&As[(wr*64+fr*16+(lane&15))*72 + kc*32 + ((lane>>4)<<3)];
      #pragma unroll
      for (int fc=0;fc<4;fc++) bq[fc] = *(const sh8*)&Bs[(wc*64+fc*16+(lane&15))*72 + kc*32 + ((lane>>4)<<3)];
      #pragma unroll
      for (int fr=0;fr<4;fr++){
        #pragma unroll
        for (int fc=0;fc<4;fc++)
          acc[fr][fc] = __builtin_amdgcn_mfma_f32_16x16x32_bf16(a[fr], bq[fc], acc[fr][fc], 0,0,0);
      }
    }
  }
  #pragma unroll
  for (int fr=0;fr<4;fr++){
    #pragma unroll
    for (int fc=0;fc<4;fc++){
      #pragma unroll
      for (int j=0;j<4;j++){
        int r = r0 + wr*64 + fr*16 + ((lane>>4)<<2) + j;
        int c = c0 + wc*64 + fc*16 + (lane&15);
        float val = acc[fr][fc][j];
        int which = c>>9, hh = (c>>6)&7, d = c&63;
        int bb = r>>12, n = r&4095;
        if (which==0) val *= 0.125f; // SCALE
        u16* dst = which==0 ? q : (which==1 ? k : v);
        dst[(((size_t)(bb*8+hh))*4096 + n)*64 + d] = f2bf(val);
      }
    }
  }
}

// ---------------- landmarks: mean over chunks of 16 ----------------
__global__ __launch_bounds__(64) void landmark_kernel(const u16* __restrict__ q,
    const u16* __restrict__ k, u16* __restrict__ ql, u16* __restrict__ kl){
  int bh = blockIdx.x, m = blockIdx.y, d = threadIdx.x;
  const u16* qp = q + (((size_t)bh*4096) + m*16)*64 + d;
  const u16* kp = k + (((size_t)bh*4096) + m*16)*64 + d;
  float sq=0, sk=0;
  #pragma unroll
  for (int j=0;j<16;j++){ sq += bf2f(qp[j*64]); sk += bf2f(kp[j*64]); }
  ql[((size_t)bh*256+m)*64+d] = f2bf(sq*(1.f/16.f));
  kl[((size_t)bh*256+m)*64+d] = f2bf(sk*(1.f/16.f));
}

// ---------------- attn2 = softmax(q_l @ k_l^T) f32 (32x256x256) ----------------
__global__ __launch_bounds__(256) void attn2_kernel(const u16* __restrict__ ql,
    const u16* __restrict__ kl, float* __restrict__ X){
  int bh = blockIdx.x, rb = blockIdx.y;
  __shared__ short klds[256*72];
  const u16* kg = kl + (size_t)bh*256*64;
  int tid = threadIdx.x;
  #pragma unroll
  for (int i=0;i<8;i++){
    int c = i*256+tid, row = c>>3, kgi = c&7;
    *(sh8*)&klds[row*72+kgi*8] = *(const sh8*)(kg + row*64 + kgi*8);
  }
  __syncthreads();
  int r = rb*16 + (tid>>4), t = tid&15;
  const u16* qr = ql + ((size_t)bh*256 + r)*64;
  float qv[64];
  #pragma unroll
  for (int i=0;i<8;i++){
    sh8 v8 = *(const sh8*)(qr + i*8);
    #pragma unroll
    for (int j=0;j<8;j++) qv[i*8+j] = bf2f((u16)v8[j]);
  }
  float s[16];
  #pragma unroll
  for (int j=0;j<16;j++){
    int col = t + 16*j;
    const short* kr = &klds[col*72];
    float accv=0;
    #pragma unroll
    for (int i8=0;i8<8;i8++){
      sh8 kv = *(const sh8*)(kr + i8*8);
      #pragma unroll
      for (int jj=0;jj<8;jj++) accv += qv[i8*8+jj]*bf2f((u16)kv[jj]);
    }
    s[j]=accv;
  }
  float mx = s[0];
  #pragma unroll
  for (int j=1;j<16;j++) mx = fmaxf(mx, s[j]);
  #pragma unroll
  for (int o=1;o<16;o<<=1) mx = fmaxf(mx, __shfl_xor(mx,o));
  float sum=0;
  #pragma unroll
  for (int j=0;j<16;j++){ s[j] = __expf(s[j]-mx); sum += s[j]; }
  #pragma unroll
  for (int o=1;o<16;o<<=1) sum += __shfl_xor(sum,o);
  float inv = 1.f/sum;
  float* Xr = X + ((size_t)bh*256 + r)*256;
  #pragma unroll
  for (int j=0;j<16;j++) Xr[t+16*j] = s[j]*inv;
}

// ---------------- global col/row scalars for pinv init ----------------
__global__ __launch_bounds__(256) void colrow_kernel(const float* __restrict__ X, float* __restrict__ scal){
  int bh = blockIdx.x, t = threadIdx.x;
  const float* x = X + (size_t)bh*65536;
  float cs=0, rs=0;
  for (int m=0;m<256;m++) cs += x[m*256+t];   // column-t sum
  for (int c=0;c<256;c++) rs += x[t*256+c];   // row-t sum
  #pragma unroll
  for (int o=32;o;o>>=1){ cs = fmaxf(cs, __shfl_xor(cs,o)); rs = fmaxf(rs, __shfl_xor(rs,o)); }
  __shared__ float sb[4], sb2[4];
  if ((t&63)==0){ sb[t>>6]=cs; sb2[t>>6]=rs; }
  __syncthreads();
  if (t==0){
    float mc = fmaxf(fmaxf(sb[0],sb[1]),fmaxf(sb[2],sb[3]));   // max col-sum -> "row"
    float mr = fmaxf(fmaxf(sb2[0],sb2[1]),fmaxf(sb2[2],sb2[3]));// max row-sum -> "col"
    atomicMax((unsigned*)&scal[1], __float_as_uint(mc));
    atomicMax((unsigned*)&scal[0], __float_as_uint(mr));
  }
}

__global__ __launch_bounds__(256) void zinit_kernel(const float* __restrict__ X,
    const float* __restrict__ scal, float* __restrict__ Z){
  int bh = blockIdx.x, i = blockIdx.y, t = threadIdx.x;
  float inv = 1.f/(scal[0]*scal[1]);
  Z[((size_t)bh*256 + i)*256 + t] = X[((size_t)bh*256 + t)*256 + i]*inv;
}

// ---------------- batched 256x256x256 matmul, bf16x2 split, C = alpha * A @ (beta*I - B | B) ----------------
__global__ __launch_bounds__(256) void pinv_mm(const float* __restrict__ Aall,
    const float* __restrict__ Ball, float* __restrict__ Call, float beta, int mode, float alpha){
  int bh = blockIdx.z, r0 = blockIdx.x*64, c0 = blockIdx.y*64;
  const float* A  = Aall + (size_t)bh*65536;
  const float* Bm = Ball + (size_t)bh*65536;
  float* C = Call + (size_t)bh*65536;
  __shared__ short Ah[64*40], Al[64*40], Bh2[64*40], Bl[64*40];
  int tid=threadIdx.x, lane=tid&63, w=tid>>6, wr=w>>1, wc=w&1;
  f4 acc[2][2];
  #pragma unroll
  for (int i=0;i<2;i++){
    #pragma unroll
    for (int j=0;j<2;j++) acc[i][j]=0;
  }
  for (int kt=0;kt<8;kt++){
    __syncthreads();
    #pragma unroll
    for (int i=0;i<2;i++){
      int c4 = i*256+tid, row = c4>>3, k4 = (c4&7)*4;
      float4 vv = *(const float4*)(A + (size_t)(r0+row)*256 + kt*32 + k4);
      float fv[4] = {vv.x, vv.y, vv.z, vv.w};
      sh4 hi, lo;
      #pragma unroll
      for (int j=0;j<4;j++){
        u16 hb = f2bf(fv[j]); float fh = bf2f(hb);
        hi[j] = (short)hb; lo[j] = (short)f2bf(fv[j]-fh);
      }
      *(sh4*)&Ah[row*40+k4] = hi; *(sh4*)&Al[row*40+k4] = lo;
    }
    #pragma unroll
    for (int i=0;i<8;i++){
      int ci = i*256+tid, col = ci&63, kk = ci>>6;
      float f = Bm[(size_t)(kt*32+kk)*256 + c0+col];
      if (mode) f = ((kt*32+kk)==(c0+col)? beta:0.f) - f;
      u16 hb = f2bf(f); float fh = bf2f(hb);
      Bh2[col*40+kk] = (short)hb; Bl[col*40+kk] = (short)f2bf(f-fh);
    }
    __syncthreads();
    sh8 ah[2], al[2], bh8[2], bl8[2];
    #pragma unroll
    for (int fr=0;fr<2;fr++){
      int off = (wr*32+fr*16+(lane&15))*40 + ((lane>>4)<<3);
      ah[fr] = *(const sh8*)&Ah[off]; al[fr] = *(const sh8*)&Al[off];
    }
    #pragma unroll
    for (int fc=0;fc<2;fc++){
      int off = (wc*32+fc*16+(lane&15))*40 + ((lane>>4)<<3);
      bh8[fc] = *(const sh8*)&Bh2[off]; bl8[fc] = *(const sh8*)&Bl[off];
    }
    #pragma unroll
    for (int fr=0;fr<2;fr++){
      #pragma unroll
      for (int fc=0;fc<2;fc++){
        acc[fr][fc] = __builtin_amdgcn_mfma_f32_16x16x32_bf16(ah[fr], bh8[fc], acc[fr][fc], 0,0,0);
        acc[fr][fc] = __builtin_amdgcn_mfma_f32_16x16x32_bf16(ah[fr], bl8[fc], acc[fr][fc], 0,0,0);
        acc[fr][fc] = __builtin_amdgcn_mfma_f32_16x16x32_bf16(al[fr], bh8[fc], acc[fr][fc], 0,0,0);
      }
    }
  }
  #pragma unroll
  for (int fr=0;fr<2;fr++){
    #pragma unroll
    for (int fc=0;fc<2;fc++){
      #pragma unroll
      for (int j=0;j<4;j++)
        C[(size_t)(r0+wr*32+fr*16+((lane>>4)<<2)+j)*256 + c0+wc*32+fc*16+(lane&15)] = alpha*acc[fr][fc][j];
    }
  }
}

// ---------------- logits GEMM (K=64): O[r][c] = A[r]·Bt[c], f16 out ----------------
__global__ __launch_bounds__(256) void gemm_logits(const u16* __restrict__ Aall,
    const u16* __restrict__ Btall, __half* __restrict__ Oall,
    int N, size_t sA, size_t sB, size_t sO){
  int bh = blockIdx.z;
  const u16* A  = Aall  + (size_t)bh*sA + (size_t)blockIdx.x*128*64;
  const u16* Bt = Btall + (size_t)bh*sB + (size_t)blockIdx.y*128*64;
  __half* O = Oall + (size_t)bh*sO + (size_t)blockIdx.x*128*N + (size_t)blockIdx.y*128;
  __shared__ short As[128*72], Bs[128*72];
  int tid=threadIdx.x, lane=tid&63, w=tid>>6, wr=w>>1, wc=w&1;
  #pragma unroll
  for (int i=0;i<4;i++){
    int c=i*256+tid, row=c>>3, kg=c&7;
    *(sh8*)&As[row*72+kg*8] = *(const sh8*)(A  + (size_t)row*64 + kg*8);
    *(sh8*)&Bs[row*72+kg*8] = *(const sh8*)(Bt + (size_t)row*64 + kg*8);
  }
  __syncthreads();
  f4 acc[4][4];
  #pragma unroll
  for (int i=0;i<4;i++){
    #pragma unroll
    for (int j=0;j<4;j++) acc[i][j]=0;
  }
  #pragma unroll
  for (int kc=0;kc<2;kc++){
    sh8 a[4], bq[4];
    #pragma unroll
    for (int fr=0;fr<4;fr++) a[fr]  = *(const sh8*)&As[(wr*64+fr*16+(lane&15))*72 + kc*32 + ((lane>>4)<<3)];
    #pragma unroll
    for (int fc=0;fc<4;fc++) bq[fc] = *(const sh8*)&Bs[(wc*64+fc*16+(lane&15))*72 + kc*32 + ((lane>>4)<<3)];
    #pragma unroll
    for (int fr=0;fr<4;fr++){
      #pragma unroll
      for (int fc=0;fc<4;fc++)
        acc[fr][fc] = __builtin_amdgcn_mfma_f32_16x16x32_bf16(a[fr], bq[fc], acc[fr][fc], 0,0,0);
    }
  }
  #pragma unroll
  for (int fr=0;fr<4;fr++){
    #pragma unroll
    for (int fc=0;fc<4;fc++){
      #pragma unroll
      for (int j=0;j<4;j++)
        O[(size_t)(wr*64+fr*16+((lane>>4)<<2)+j)*N + wc*64+fc*16+(lane&15)] = __float2half(acc[fr][fc][j]);
    }
  }
}

// ---------------- row stats (max, 1/sumexp) over RL f16 logits ----------------
__global__ __launch_bounds__(256) void stats_kernel(const __half* __restrict__ logits,
    float2* __restrict__ stats, int RL){
  size_t row = blockIdx.x;
  const __half2* p = (const __half2*)(logits + row*RL);
  int t = threadIdx.x, n2 = RL>>1;
  float mx = -1e30f;
  for (int i=t;i<n2;i+=256){ float2 f = __half22float2(p[i]); mx = fmaxf(mx, fmaxf(f.x,f.y)); }
  #pragma unroll
  for (int o=32;o;o>>=1) mx = fmaxf(mx, __shfl_xor(mx,o));
  __shared__ float sb[4], sb2[4];
  if ((t&63)==0) sb[t>>6]=mx;
  __syncthreads();
  mx = fmaxf(fmaxf(sb[0],sb[1]),fmaxf(sb[2],sb[3]));
  float s=0;
  for (int i=t;i<n2;i+=256){ float2 f = __half22float2(p[i]); s += __expf(f.x-mx)+__expf(f.y-mx); }
  #pragma unroll
  for (int o=32;o;o>>=1) s += __shfl_xor(s,o);
  if ((t&63)==0) sb2[t>>6]=s;
  __syncthreads();
  s = sb2[0]+sb2[1]+sb2[2]+sb2[3];
  if (t==0) stats[row] = make_float2(mx, 1.f/s);
}

// ---------------- out3 = softmax(logits3) @ v : (256x4096)@(4096x64) per bh ----------------
__global__ __launch_bounds__(256) void gemm_out3(const __half* __restrict__ Lall,
    const float2* __restrict__ stall, const u16* __restrict__ vall, float* __restrict__ Oall){
  int bh = blockIdx.z, mt = blockIdx.x;
  const __half* L = Lall + (size_t)bh*256*4096 + (size_t)mt*128*4096;
  const float2* st = stall + (size_t)bh*256 + mt*128;
  const u16* V = vall + (size_t)bh*4096*64;
  float* O = Oall + (size_t)bh*256*64 + (size_t)mt*128*64;
  __shared__ short As[128*72], Bs[64*72];
  int tid=threadIdx.x, lane=tid&63, w=tid>>6;
  f4 acc[2][4];
  #pragma unroll
  for (int i=0;i<2;i++){
    #pragma unroll
    for (int j=0;j<4;j++) acc[i][j]=0;
  }
  for (int kt=0;kt<64;kt++){
    __syncthreads();
    #pragma unroll
    for (int i=0;i<4;i++){
      int c=i*256+tid, row=c>>3, kg=c&7;
      const __half2* src = (const __half2*)(L + (size_t)row*4096 + kt*64 + kg*8);
      float2 ms = st[row];
      sh8 ov;
      #pragma unroll
      for (int jj=0;jj<4;jj++){
        float2 f = __half22float2(src[jj]);
        ov[2*jj]   = (short)f2bf(__expf(f.x-ms.x)*ms.y);
        ov[2*jj+1] = (short)f2bf(__expf(f.y-ms.x)*ms.y);
      }
      *(sh8*)&As[row*72+kg*8] = ov;
    }
    #pragma unroll
    for (int i=0;i<16;i++){
      int c=i*256+tid, d=c&63, nl=c>>6;
      Bs[d*72+nl] = (short)V[(size_t)(kt*64+nl)*64 + d];
    }
    __syncthreads();
    #pragma unroll
    for (int kc=0;kc<2;kc++){
      sh8 a[2], bq[4];
      #pragma unroll
      for (int fr=0;fr<2;fr++) a[fr]  = *(const sh8*)&As[(w*32+fr*16+(lane&15))*72 + kc*32+((lane>>4)<<3)];
      #pragma unroll
      for (int fc=0;fc<4;fc++) bq[fc] = *(const sh8*)&Bs[(fc*16+(lane&15))*72 + kc*32+((lane>>4)<<3)];
      #pragma unroll
      for (int fr=0;fr<2;fr++){
        #pragma unroll
        for (int fc=0;fc<4;fc++)
          acc[fr][fc] = __builtin_amdgcn_mfma_f32_16x16x32_bf16(a[fr], bq[fc], acc[fr][fc], 0,0,0);
      }
    }
  }
  #pragma unroll
  for (int fr=0;fr<2;fr++){
    #pragma unroll
    for (int fc=0;fc<4;fc++){
      #pragma unroll
      for (int j=0;j<4;j++)
        O[(size_t)(w*32+fr*16+((lane>>4)<<2)+j)*64 + fc*16+(lane&15)] = acc[fr][fc][j];
    }
  }
}

// ---------------- Wt[d][m] = (z @ out3)[m][d] bf16 ----------------
__global__ __launch_bounds__(256) void wt_kernel(const float* __restrict__ Z,
    const float* __restrict__ o3, u16* __restrict__ Wt){
  int bh = blockIdx.x; int m = blockIdx.y*4 + (threadIdx.x>>6); int d = threadIdx.x&63;
  const float* zr = Z + ((size_t)bh*256 + m)*256;
  const float* op = o3 + (size_t)bh*256*64 + d;
  float accv = 0;
  for (int kk=0;kk<256;kk++) accv += zr[kk]*op[kk*64];
  Wt[((size_t)bh*64 + d)*256 + m] = f2bf(accv);
}

// ---------------- out1 = softmax(logits1) @ W : (4096x256)@(256x64) per bh ----------------
__global__ __launch_bounds__(256) void gemm_out1(const __half* __restrict__ Lall,
    const float2* __restrict__ stall, const u16* __restrict__ Wtall, float* __restrict__ Oall){
  int bh = blockIdx.z, mt = blockIdx.x;
  const __half* L = Lall + (size_t)bh*4096*256 + (size_t)mt*128*256;
  const float2* st = stall + (size_t)bh*4096 + mt*128;
  const u16* Wt = Wtall + (size_t)bh*64*256;
  float* O = Oall + ((size_t)bh*4096 + (size_t)mt*128)*64;
  __shared__ short As[128*72], Bs[64*72];
  int tid=threadIdx.x, lane=tid&63, w=tid>>6;
  f4 acc[2][4];
  #pragma unroll
  for (int i=0;i<2;i++){
    #pragma unroll
    for (int j=0;j<4;j++) acc[i][j]=0;
  }
  for (int kt=0;kt<4;kt++){
    __syncthreads();
    #pragma unroll
    for (int i=0;i<4;i++){
      int c=i*256+tid, row=c>>3, kg=c&7;
      const __half2* src = (const __half2*)(L + (size_t)row*256 + kt*64 + kg*8);
      float2 ms = st[row];
      sh8 ov;
      #pragma unroll
      for (int jj=0;jj<4;jj++){
        float2 f = __half22float2(src[jj]);
        ov[2*jj]   = (short)f2bf(__expf(f.x-ms.x)*ms.y);
        ov[2*jj+1] = (short)f2bf(__expf(f.y-ms.x)*ms.y);
      }
      *(sh8*)&As[row*72+kg*8] = ov;
    }
    #pragma unroll
    for (int i=0;i<2;i++){
      int c=i*256+tid, row=c>>3, kg=c&7;
      *(sh8*)&Bs[row*72+kg*8] = *(const sh8*)(Wt + (size_t)row*256 + kt*64 + kg*8);
    }
    __syncthreads();
    #pragma unroll
    for (int kc=0;kc<2;kc++){
      sh8 a[2], bq[4];
      #pragma unroll
      for (int fr=0;fr<2;fr++) a[fr]  = *(const sh8*)&As[(w*32+fr*16+(lane&15))*72 + kc*32+((lane>>4)<<3)];
      #pragma unroll
      for (int fc=0;fc<4;fc++) bq[fc] = *(const sh8*)&Bs[(fc*16+(lane&15))*72 + kc*32+((lane>>4)<<3)];
      #pragma unroll
      for (int fr=0;fr<2;fr++){
        #pragma unroll
        for (int fc=0;fc<4;fc++)
          acc[fr][fc] = __builtin_amdgcn_mfma_f32_16x16x32_bf16(a[fr], bq[fc], acc[fr][fc], 0,0,0);
      }
    }
  }
  #pragma unroll
  for (int fr=0;fr<2;fr++){
    #pragma unroll
    for (int fc=0;fc<4;fc++){
      #pragma unroll
      for (int j=0;j<4;j++)
        O[(size_t)(w*32+fr*16+((lane>>4)<<2)+j)*64 + fc*16+(lane&15)] = acc[fr][fc][j];
    }
  }
}

// ---------------- combine: ocomb = bf16(out1 + depthwise_conv33(v)), layout (b,n,h*64+d) ----------------
__global__ __launch_bounds__(256) void combine_kernel(const float* __restrict__ out1,
    const u16* __restrict__ v, const float* __restrict__ wres, u16* __restrict__ oc){
  int bh = blockIdx.x; int hh = bh&7, bb = bh>>3;
  int n = blockIdx.y*4 + (threadIdx.x>>6); int d = threadIdx.x&63;
  float accv = out1[(((size_t)bh*4096)+n)*64 + d];
  const u16* vb = v + ((size_t)bh*4096)*64 + d;
  #pragma unroll
  for (int j=0;j<33;j++){
    int nn = n + j - 16;
    if (nn>=0 && nn<4096) accv += wres[hh*33+j]*bf2f(vb[(size_t)nn*64]);
  }
  oc[((size_t)(bb*4096+n))*512 + hh*64 + d] = f2bf(accv);
}

// ---------------- final: out = x + ocomb @ w_out + b_out ----------------
__global__ __launch_bounds__(256) void gemm_final(const u16* __restrict__ A,
    const u16* __restrict__ Bt, const float* __restrict__ x, const float* __restrict__ bo,
    float* __restrict__ out){
  __shared__ short As[128*72], Bs[128*72];
  int r0 = blockIdx.x*128, c0 = blockIdx.y*128;
  int tid = threadIdx.x, lane = tid&63, w = tid>>6;
  int wr = w>>1, wc = w&1;
  f4 acc[4][4];
  #pragma unroll
  for (int i=0;i<4;i++){
    #pragma unroll
    for (int j=0;j<4;j++) acc[i][j]=0;
  }
  for (int kt=0;kt<8;kt++){
    __syncthreads();
    #pragma unroll
    for (int i=0;i<4;i++){
      int c = i*256+tid, row = c>>3, kg = c&7;
      *(sh8*)&As[row*72+kg*8] = *(const sh8*)(A  + (size_t)(r0+row)*512 + kt*64 + kg*8);
      *(sh8*)&Bs[row*72+kg*8] = *(const sh8*)(Bt + (size_t)(c0+row)*512 + kt*64 + kg*8);
    }
    __syncthreads();
    #pragma unroll
    for (int kc=0;kc<2;kc++){
      sh8 a[4], bq[4];
      #pragma unroll
      for (int fr=0;fr<4;fr++) a[fr]  = *(const sh8*)&As[(wr*64+fr*16+(lane&15))*72 + kc*32 + ((lane>>4)<<3)];
      #pragma unroll
      for (int fc=0;fc<4;fc++) bq[fc] = *(const sh8*)&Bs[(wc*64+fc*16+(lane&15))*72 + kc*32 + ((lane>>4)<<3)];
      #pragma unroll
      for (int fr=0;fr<4;fr++){
        #pragma unroll
        for (int fc=0;fc<4;fc++)
          acc[fr][fc] = __builtin_amdgcn_mfma_f32_16x16x32_bf16(a[fr], bq[fc], acc[fr][fc], 0,0,0);
      }
    }
  }
  #pragma unroll
  for (int fr=0;fr<4;fr++){
    #pragma unroll
    for (int fc=0;fc<4;fc++){
      #pragma unroll
      for (int j=0;j<4;j++){
        int r = r0 + wr*64 + fr*16 + ((lane>>4)<<2) + j;
        int c = c0 + wc*64 + fc*16 + (lane&15);
        out[(size_t)r*512+c] = x[(size_t)r*512+c] + acc[fr][fc][j] + bo[c];
      }
    }
  }
}

extern "C" void kernel_launch(void* const* d_in, const int* in_sizes, int n_in,
                              void* d_out, int out_size, void* d_ws, size_t ws_size,
                              hipStream_t stream){
  const float* x    = (const float*)d_in[0];
  const float* lnw  = (const float*)d_in[1];
  const float* lnb  = (const float*)d_in[2];
  const float* wqkv = (const float*)d_in[3];
  const float* wout = (const float*)d_in[4];
  const float* bout = (const float*)d_in[5];
  const float* wres = (const float*)d_in[6];
  float* out = (float*)d_out;

  char* ws = (char*)d_ws;
  size_t off = 0;
  auto alloc = [&](size_t bytes)->void*{ void* p = ws + off; off += (bytes + 255) & ~(size_t)255; return p; };
  u16* h      = (u16*)alloc((size_t)NT_*512*2);        // aliased later as ocomb
  u16* wqkvT  = (u16*)alloc((size_t)1536*512*2);
  u16* woutT  = (u16*)alloc((size_t)512*512*2);
  u16* q      = (u16*)alloc((size_t)BH_*4096*64*2);
  u16* k      = (u16*)alloc((size_t)BH_*4096*64*2);
  u16* v      = (u16*)alloc((size_t)BH_*4096*64*2);
  u16* ql     = (u16*)alloc((size_t)BH_*256*64*2);
  u16* kl     = (u16*)alloc((size_t)BH_*256*64*2);
  float* X    = (float*)alloc((size_t)BH_*65536*4);
  float* Z0   = (float*)alloc((size_t)BH_*65536*4);
  float* Z1   = (float*)alloc((size_t)BH_*65536*4);
  float* T1   = (float*)alloc((size_t)BH_*65536*4);
  float* T2   = (float*)alloc((size_t)BH_*65536*4);
  float* T3   = (float*)alloc((size_t)BH_*65536*4);
  __half* logits = (__half*)alloc((size_t)BH_*4096*256*2);  // shared: logits3 then logits1
  float2* st3 = (float2*)alloc((size_t)BH_*256*8);
  float2* st1 = (float2*)alloc((size_t)BH_*4096*8);
  float* o3   = (float*)alloc((size_t)BH_*256*64*4);
  u16* Wt     = (u16*)alloc((size_t)BH_*64*256*2);
  float* scal = (float*)alloc(256);
  float* out1 = Z0;  // alias: 32MB spans Z0,Z1,T1,T2 (all dead by then)
  u16* oc     = h;   // alias: h dead after qkv gemm

  ln_kernel<<<NT_, 256, 0, stream>>>(x, lnw, lnb, h);
  castT_kernel<<<(512*1536+255)/256, 256, 0, stream>>>(wqkv, wqkvT, 512, 1536);
  castT_kernel<<<(512*512+255)/256, 256, 0, stream>>>(wout, woutT, 512, 512);
  gemm_qkv<<<dim3(128,12,1), 256, 0, stream>>>(h, wqkvT, q, k, v);
  landmark_kernel<<<dim3(32,256,1), 64, 0, stream>>>(q, k, ql, kl);
  attn2_kernel<<<dim3(32,16,1), 256, 0, stream>>>(ql, kl, X);
  hipMemsetAsync(scal, 0, 8, stream);
  colrow_kernel<<<32, 256, 0, stream>>>(X, scal);
  zinit_kernel<<<dim3(32,256,1), 256, 0, stream>>>(X, scal, Z0);
  float* za = Z0; float* zb = Z1;
  for (int it=0; it<6; it++){
    pinv_mm<<<dim3(4,4,32),256,0,stream>>>(X,  za, T1, 0.f,  0, 1.f);
    pinv_mm<<<dim3(4,4,32),256,0,stream>>>(T1, T1, T2, 7.f,  1, 1.f);
    pinv_mm<<<dim3(4,4,32),256,0,stream>>>(T1, T2, T3, 15.f, 1, 1.f);
    pinv_mm<<<dim3(4,4,32),256,0,stream>>>(za, T3, zb, 13.f, 1, 0.25f);
    float* tmp = za; za = zb; zb = tmp;
  }
  // za == Z0 holds the final pinv
  gemm_logits<<<dim3(2,32,32),256,0,stream>>>(ql, k, logits, 4096,
      (size_t)256*64, (size_t)4096*64, (size_t)256*4096);
  stats_kernel<<<BH_*256, 256, 0, stream>>>(logits, st3, 4096);
  gemm_out3<<<dim3(2,1,32),256,0,stream>>>(logits, st3, v, o3);
  wt_kernel<<<dim3(32,64,1),256,0,stream>>>(za, o3, Wt);
  gemm_logits<<<dim3(32,2,32),256,0,stream>>>(q, kl, logits, 256,
      (size_t)4096*64, (size_t)256*64, (size_t)4096*256);
  stats_kernel<<<BH_*4096, 256, 0, stream>>>(logits, st1, 256);
  gemm_out1<<<dim3(32,1,32),256,0,stream>>>(logits, st1, Wt, out1);
  combine_kernel<<<dim3(32,1024,1),256,0,stream>>>(out1, v, wres, oc);
  gemm_final<<<dim3(128,4,1),256,0,stream>>>(oc, woutT, x, bout, out);
}

// Round 2
// 693.691 us; speedup vs baseline: 1.2351x; 1.2351x over previous
//
#include <hip/hip_runtime.h>
#include <hip/hip_bf16.h>
#include <hip/hip_fp16.h>

// Nystromformer layer: b=4, n=4096, dim=512, heads=8, dim_head=64, m=256, pinv_iters=6
#define B_ 4
#define H_ 8
#define N_ 4096
#define DH_ 64
#define D_ 512
#define M_ 256
#define BH_ 32
#define NT_ 16384

typedef unsigned short u16;
using sh8 = __attribute__((ext_vector_type(8))) short;
using sh4 = __attribute__((ext_vector_type(4))) short;
using f4  = __attribute__((ext_vector_type(4))) float;

__device__ __forceinline__ float bf2f(u16 u){ return __uint_as_float(((unsigned)u)<<16); }
__device__ __forceinline__ u16 f2bf(float f){
  unsigned u = __float_as_uint(f);
  u += 0x7fffu + ((u>>16)&1u);
  return (u16)(u>>16);
}

// ---------------- LayerNorm: x f32 (16384x512) -> h bf16 ----------------
__global__ __launch_bounds__(256) void ln_kernel(const float* __restrict__ x,
    const float* __restrict__ w, const float* __restrict__ b, u16* __restrict__ h){
  int row = blockIdx.x;
  const float2* xr = (const float2*)(x + (size_t)row*D_);
  int t = threadIdx.x;
  float2 v = xr[t];
  float s = v.x+v.y, ss = v.x*v.x+v.y*v.y;
  #pragma unroll
  for (int o=32;o;o>>=1){ s += __shfl_xor(s,o); ss += __shfl_xor(ss,o); }
  __shared__ float sb[4], sb2[4];
  if ((t&63)==0){ sb[t>>6]=s; sb2[t>>6]=ss; }
  __syncthreads();
  float ts  = sb[0]+sb[1]+sb[2]+sb[3];
  float tss = sb2[0]+sb2[1]+sb2[2]+sb2[3];
  float mean = ts*(1.f/D_);
  float var  = tss*(1.f/D_) - mean*mean;
  float rstd = rsqrtf(var+1e-5f);
  int c = 2*t;
  float o0 = (v.x-mean)*rstd*w[c]   + b[c];
  float o1 = (v.y-mean)*rstd*w[c+1] + b[c+1];
  u16* hr = h + (size_t)row*D_;
  hr[c] = f2bf(o0); hr[c+1] = f2bf(o1);
}

// ---------------- transpose-cast f32 [K][N] -> bf16 [N][K] ----------------
__global__ void castT_kernel(const float* __restrict__ in, u16* __restrict__ out, int K, int N){
  int idx = blockIdx.x*256 + threadIdx.x;
  if (idx < K*N){ int k = idx/N, n = idx - k*N; out[(size_t)n*K + k] = f2bf(in[idx]); }
}

// ---------------- QKV GEMM: h(16384x512) @ wqkvT(1536x512)^T, scatter q,k,v ----------------
__global__ __launch_bounds__(256) void gemm_qkv(const u16* __restrict__ A,
    const u16* __restrict__ Bt, u16* __restrict__ q, u16* __restrict__ k, u16* __restrict__ v){
  __shared__ short As[128*72], Bs[128*72];
  int r0 = blockIdx.x*128, c0 = blockIdx.y*128;
  int tid = threadIdx.x, lane = tid&63, w = tid>>6;
  int wr = w>>1, wc = w&1;
  f4 acc[4][4];
  #pragma unroll
  for (int i=0;i<4;i++){
    #pragma unroll
    for (int j=0;j<4;j++) acc[i][j]=0;
  }
  for (int kt=0;kt<8;kt++){
    __syncthreads();
    #pragma unroll
    for (int i=0;i<4;i++){
      int c = i*256+tid, row = c>>3, kg = c&7;
      *(sh8*)&As[row*72+kg*8] = *(const sh8*)(A + (size_t)(r0+row)*512 + kt*64 + kg*8);
      *(sh8*)&Bs[row*72+kg*8] = *(const sh8*)(Bt + (size_t)(c0+row)*512 + kt*64 + kg*8);
    }
    __syncthreads();
    #pragma unroll
    for (int kc=0;kc<2;kc++){
      sh8 a[4], bq[4];
      #pragma unroll
      for (int fr=0;fr<4;fr++) a[fr]  = *(const sh8*)&As[(wr*64+fr*16+(lane&15))*72 + kc*32 + ((lane>>4)<<3)];
      #pragma unroll
      for (int fc=0;fc<4;fc++) bq[fc] = *(const sh8*)&Bs[(wc*64+fc*16+(lane&15))*72 + kc*32 + ((lane>>4)<<3)];
      #pragma unroll
      for (int fr=0;fr<4;fr++){
        #pragma unroll
        for (int fc=0;fc<4;fc++)
          acc[fr][fc] = __builtin_amdgcn_mfma_f32_16x16x32_bf16(a[fr], bq[fc], acc[fr][fc], 0,0,0);
      }
    }
  }
  #pragma unroll
  for (int fr=0;fr<4;fr++){
    #pragma unroll
    for (int fc=0;fc<4;fc++){
      #pragma unroll
      for (int j=0;j<4;j++){
        int r = r0 + wr*64 + fr*16 + ((lane>>4)<<2) + j;
        int c = c0 + wc*64 + fc*16 + (lane&15);
        float val = acc[fr][fc][j];
        int which = c>>9, hh = (c>>6)&7, d = c&63;
        int bb = r>>12, n = r&4095;
        if (which==0) val *= 0.125f; // SCALE
        u16* dst = which==0 ? q : (which==1 ? k : v);
        dst[(((size_t)(bb*8+hh))*4096 + n)*64 + d] = f2bf(val);
      }
    }
  }
}

// ---------------- landmarks: mean over chunks of 16 ----------------
__global__ __launch_bounds__(64) void landmark_kernel(const u16* __restrict__ q,
    const u16* __restrict__ k, u16* __restrict__ ql, u16* __restrict__ kl){
  int bh = blockIdx.x, m = blockIdx.y, d = threadIdx.x;
  const u16* qp = q + (((size_t)bh*4096) + m*16)*64 + d;
  const u16* kp = k + (((size_t)bh*4096) + m*16)*64 + d;
  float sq=0, sk=0;
  #pragma unroll
  for (int j=0;j<16;j++){ sq += bf2f(qp[j*64]); sk += bf2f(kp[j*64]); }
  ql[((size_t)bh*256+m)*64+d] = f2bf(sq*(1.f/16.f));
  kl[((size_t)bh*256+m)*64+d] = f2bf(sk*(1.f/16.f));
}

// ---------------- attn2 = softmax(q_l @ k_l^T) -> bf16 hi/lo split (32x256x256) ----------------
__global__ __launch_bounds__(256) void attn2_kernel(const u16* __restrict__ ql,
    const u16* __restrict__ kl, u16* __restrict__ Xhi, u16* __restrict__ Xlo){
  int bh = blockIdx.x, rb = blockIdx.y;
  __shared__ short klds[256*72];
  const u16* kg = kl + (size_t)bh*256*64;
  int tid = threadIdx.x;
  #pragma unroll
  for (int i=0;i<8;i++){
    int c = i*256+tid, row = c>>3, kgi = c&7;
    *(sh8*)&klds[row*72+kgi*8] = *(const sh8*)(kg + row*64 + kgi*8);
  }
  __syncthreads();
  int r = rb*16 + (tid>>4), t = tid&15;
  const u16* qr = ql + ((size_t)bh*256 + r)*64;
  float qv[64];
  #pragma unroll
  for (int i=0;i<8;i++){
    sh8 v8 = *(const sh8*)(qr + i*8);
    #pragma unroll
    for (int j=0;j<8;j++) qv[i*8+j] = bf2f((u16)v8[j]);
  }
  float s[16];
  #pragma unroll
  for (int j=0;j<16;j++){
    int col = t + 16*j;
    const short* kr = &klds[col*72];
    float accv=0;
    #pragma unroll
    for (int i8=0;i8<8;i8++){
      sh8 kv = *(const sh8*)(kr + i8*8);
      #pragma unroll
      for (int jj=0;jj<8;jj++) accv += qv[i8*8+jj]*bf2f((u16)kv[jj]);
    }
    s[j]=accv;
  }
  float mx = s[0];
  #pragma unroll
  for (int j=1;j<16;j++) mx = fmaxf(mx, s[j]);
  #pragma unroll
  for (int o=1;o<16;o<<=1) mx = fmaxf(mx, __shfl_xor(mx,o));
  float sum=0;
  #pragma unroll
  for (int j=0;j<16;j++){ s[j] = __expf(s[j]-mx); sum += s[j]; }
  #pragma unroll
  for (int o=1;o<16;o<<=1) sum += __shfl_xor(sum,o);
  float inv = 1.f/sum;
  u16* Xh = Xhi + ((size_t)bh*256 + r)*256;
  u16* Xl = Xlo + ((size_t)bh*256 + r)*256;
  #pragma unroll
  for (int j=0;j<16;j++){
    float val = s[j]*inv;
    u16 hb = f2bf(val);
    Xh[t+16*j] = hb; Xl[t+16*j] = f2bf(val - bf2f(hb));
  }
}

// ---------------- global col/row scalars for pinv init ----------------
__global__ __launch_bounds__(256) void colrow_kernel(const u16* __restrict__ Xhi,
    const u16* __restrict__ Xlo, float* __restrict__ scal){
  int bh = blockIdx.x, t = threadIdx.x;
  const u16* xh = Xhi + (size_t)bh*65536;
  const u16* xl = Xlo + (size_t)bh*65536;
  float cs=0, rs=0;
  for (int m=0;m<256;m++) cs += bf2f(xh[m*256+t]) + bf2f(xl[m*256+t]);
  for (int c=0;c<256;c++) rs += bf2f(xh[t*256+c]) + bf2f(xl[t*256+c]);
  #pragma unroll
  for (int o=32;o;o>>=1){ cs = fmaxf(cs, __shfl_xor(cs,o)); rs = fmaxf(rs, __shfl_xor(rs,o)); }
  __shared__ float sb[4], sb2[4];
  if ((t&63)==0){ sb[t>>6]=cs; sb2[t>>6]=rs; }
  __syncthreads();
  if (t==0){
    float mc = fmaxf(fmaxf(sb[0],sb[1]),fmaxf(sb[2],sb[3]));   // max col-sum -> "row"
    float mr = fmaxf(fmaxf(sb2[0],sb2[1]),fmaxf(sb2[2],sb2[3]));// max row-sum -> "col"
    atomicMax((unsigned*)&scal[1], __float_as_uint(mc));
    atomicMax((unsigned*)&scal[0], __float_as_uint(mr));
  }
}

// ---------------- Z0 = X^T/(col*row) (hi/lo) and Z0T = X/(col*row), LDS-tiled ----------------
__global__ __launch_bounds__(256) void ztinit_kernel(const u16* __restrict__ Xhi,
    const u16* __restrict__ Xlo, const float* __restrict__ scal,
    u16* __restrict__ Zhi, u16* __restrict__ Zlo, u16* __restrict__ ZThi, u16* __restrict__ ZTlo){
  int bh = blockIdx.x; int xr0 = blockIdx.y*64, xc0 = blockIdx.z*64;
  __shared__ float tb[64*66];
  float inv = 1.f/(scal[0]*scal[1]);
  int tid = threadIdx.x;
  size_t mo = (size_t)bh*65536;
  int row = tid>>2, cof = (tid&3)*16;
  #pragma unroll
  for (int s2=0;s2<2;s2++){
    sh8 hv = *(const sh8*)(Xhi + mo + (size_t)(xr0+row)*256 + xc0+cof+s2*8);
    sh8 lv = *(const sh8*)(Xlo + mo + (size_t)(xr0+row)*256 + xc0+cof+s2*8);
    #pragma unroll
    for (int j=0;j<8;j++) tb[row*66 + cof+s2*8+j] = (bf2f((u16)hv[j])+bf2f((u16)lv[j]))*inv;
  }
  __syncthreads();
  int lc = tid&63;
  #pragma unroll
  for (int i=0;i<16;i++){
    int lr = i*4 + (tid>>6);
    float v1 = tb[lr*66+lc];         // ZT tile, same orientation as X
    u16 h1 = f2bf(v1);
    ZThi[mo + (size_t)(xr0+lr)*256 + xc0+lc] = h1;
    ZTlo[mo + (size_t)(xr0+lr)*256 + xc0+lc] = f2bf(v1 - bf2f(h1));
    float v2 = tb[lc*66+lr];         // Z[xc0+lr][xr0+lc] = X[xr0+lc][xc0+lr]*inv
    u16 h2 = f2bf(v2);
    Zhi[mo + (size_t)(xc0+lr)*256 + xr0+lc] = h2;
    Zlo[mo + (size_t)(xc0+lr)*256 + xr0+lc] = f2bf(v2 - bf2f(h2));
  }
}

// ---------------- batched 256^3 matmul, bf16x2 split in/out.
// acc = A@B (B given as BT rows). mode1: val = alpha*(beta*A[r][c] - acc).
// Writes C (row-major) and/or CT (transposed), both as hi/lo bf16. ----------------
__global__ __launch_bounds__(256) void pinv_mm(
    const u16* __restrict__ Ahi, const u16* __restrict__ Alo,
    const u16* __restrict__ Bthi, const u16* __restrict__ Btlo,
    u16* __restrict__ Chi, u16* __restrict__ Clo,
    u16* __restrict__ CThi, u16* __restrict__ CTlo,
    float beta, float alpha, int mode){
  int bh = blockIdx.z, r0 = blockIdx.x*64, c0 = blockIdx.y*64;
  size_t mo = (size_t)bh*65536;
  __shared__ __align__(16) short smem[4*64*40];   // Ah|Al|Bh|Bl ; epilogue alias: float tb[64*66]
  short* Ah = smem; short* Al = smem + 2560; short* Bh = smem + 5120; short* Bl = smem + 7680;
  int tid=threadIdx.x, lane=tid&63, w=tid>>6, wr=w>>1, wc=w&1;
  int srow = tid>>2, skof = (tid&3)*8;
  f4 acc[2][2];
  #pragma unroll
  for (int i=0;i<2;i++){
    #pragma unroll
    for (int j=0;j<2;j++) acc[i][j]=0;
  }
  for (int kt=0;kt<8;kt++){
    __syncthreads();
    *(sh8*)&Ah[srow*40+skof] = *(const sh8*)(Ahi  + mo + (size_t)(r0+srow)*256 + kt*32 + skof);
    *(sh8*)&Al[srow*40+skof] = *(const sh8*)(Alo  + mo + (size_t)(r0+srow)*256 + kt*32 + skof);
    *(sh8*)&Bh[srow*40+skof] = *(const sh8*)(Bthi + mo + (size_t)(c0+srow)*256 + kt*32 + skof);
    *(sh8*)&Bl[srow*40+skof] = *(const sh8*)(Btlo + mo + (size_t)(c0+srow)*256 + kt*32 + skof);
    __syncthreads();
    sh8 ah[2], al[2], bh8[2], bl8[2];
    #pragma unroll
    for (int fr=0;fr<2;fr++){
      int off = (wr*32+fr*16+(lane&15))*40 + ((lane>>4)<<3);
      ah[fr] = *(const sh8*)&Ah[off]; al[fr] = *(const sh8*)&Al[off];
    }
    #pragma unroll
    for (int fc=0;fc<2;fc++){
      int off = (wc*32+fc*16+(lane&15))*40 + ((lane>>4)<<3);
      bh8[fc] = *(const sh8*)&Bh[off]; bl8[fc] = *(const sh8*)&Bl[off];
    }
    #pragma unroll
    for (int fr=0;fr<2;fr++){
      #pragma unroll
      for (int fc=0;fc<2;fc++){
        acc[fr][fc] = __builtin_amdgcn_mfma_f32_16x16x32_bf16(ah[fr], bh8[fc], acc[fr][fc], 0,0,0);
        acc[fr][fc] = __builtin_amdgcn_mfma_f32_16x16x32_bf16(ah[fr], bl8[fc], acc[fr][fc], 0,0,0);
        acc[fr][fc] = __builtin_amdgcn_mfma_f32_16x16x32_bf16(al[fr], bh8[fc], acc[fr][fc], 0,0,0);
      }
    }
  }
  __syncthreads();
  float* tb = (float*)smem;
  #pragma unroll
  for (int fr=0;fr<2;fr++){
    #pragma unroll
    for (int fc=0;fc<2;fc++){
      #pragma unroll
      for (int j=0;j<4;j++){
        int lr = wr*32+fr*16+((lane>>4)<<2)+j, lc = wc*32+fc*16+(lane&15);
        float val = acc[fr][fc][j];
        if (mode){
          float av = bf2f(Ahi[mo+(size_t)(r0+lr)*256+c0+lc]) + bf2f(Alo[mo+(size_t)(r0+lr)*256+c0+lc]);
          val = alpha*(beta*av - val);
        }
        tb[lr*66+lc] = val;
      }
    }
  }
  __syncthreads();
  int lc2 = tid&63;
  #pragma unroll
  for (int i=0;i<16;i++){
    int lr2 = i*4+(tid>>6);
    if (Chi){
      float v1 = tb[lr2*66+lc2];
      u16 hb=f2bf(v1);
      Chi[mo+(size_t)(r0+lr2)*256+c0+lc2]=hb;
      Clo[mo+(size_t)(r0+lr2)*256+c0+lc2]=f2bf(v1-bf2f(hb));
    }
    if (CThi){
      float v2 = tb[lc2*66 + lr2];   // CT[c0+lr2][r0+lc2] = C[r0+lc2][c0+lr2]
      u16 hb2=f2bf(v2);
      CThi[mo+(size_t)(c0+lr2)*256 + r0+lc2]=hb2;
      CTlo[mo+(size_t)(c0+lr2)*256 + r0+lc2]=f2bf(v2-bf2f(hb2));
    }
  }
}

// ---------------- logits GEMM (K=64): O[r][c] = A[r]·Bt[c], f16 out ----------------
__global__ __launch_bounds__(256) void gemm_logits(const u16* __restrict__ Aall,
    const u16* __restrict__ Btall, __half* __restrict__ Oall,
    int N, size_t sA, size_t sB, size_t sO){
  int bh = blockIdx.z;
  const u16* A  = Aall  + (size_t)bh*sA + (size_t)blockIdx.x*128*64;
  const u16* Bt = Btall + (size_t)bh*sB + (size_t)blockIdx.y*128*64;
  __half* O = Oall + (size_t)bh*sO + (size_t)blockIdx.x*128*N + (size_t)blockIdx.y*128;
  __shared__ short As[128*72], Bs[128*72];
  int tid=threadIdx.x, lane=tid&63, w=tid>>6, wr=w>>1, wc=w&1;
  #pragma unroll
  for (int i=0;i<4;i++){
    int c=i*256+tid, row=c>>3, kg=c&7;
    *(sh8*)&As[row*72+kg*8] = *(const sh8*)(A  + (size_t)row*64 + kg*8);
    *(sh8*)&Bs[row*72+kg*8] = *(const sh8*)(Bt + (size_t)row*64 + kg*8);
  }
  __syncthreads();
  f4 acc[4][4];
  #pragma unroll
  for (int i=0;i<4;i++){
    #pragma unroll
    for (int j=0;j<4;j++) acc[i][j]=0;
  }
  #pragma unroll
  for (int kc=0;kc<2;kc++){
    sh8 a[4], bq[4];
    #pragma unroll
    for (int fr=0;fr<4;fr++) a[fr]  = *(const sh8*)&As[(wr*64+fr*16+(lane&15))*72 + kc*32 + ((lane>>4)<<3)];
    #pragma unroll
    for (int fc=0;fc<4;fc++) bq[fc] = *(const sh8*)&Bs[(wc*64+fc*16+(lane&15))*72 + kc*32 + ((lane>>4)<<3)];
    #pragma unroll
    for (int fr=0;fr<4;fr++){
      #pragma unroll
      for (int fc=0;fc<4;fc++)
        acc[fr][fc] = __builtin_amdgcn_mfma_f32_16x16x32_bf16(a[fr], bq[fc], acc[fr][fc], 0,0,0);
    }
  }
  #pragma unroll
  for (int fr=0;fr<4;fr++){
    #pragma unroll
    for (int fc=0;fc<4;fc++){
      #pragma unroll
      for (int j=0;j<4;j++)
        O[(size_t)(wr*64+fr*16+((lane>>4)<<2)+j)*N + wc*64+fc*16+(lane&15)] = __float2half(acc[fr][fc][j]);
    }
  }
}

// ---------------- row stats (max, 1/sumexp) over 4096-long f16 rows ----------------
__global__ __launch_bounds__(256) void stats_kernel(const __half* __restrict__ logits,
    float2* __restrict__ stats, int RL){
  size_t row = blockIdx.x;
  const __half2* p = (const __half2*)(logits + row*RL);
  int t = threadIdx.x, n2 = RL>>1;
  float mx = -1e30f;
  for (int i=t;i<n2;i+=256){ float2 f = __half22float2(p[i]); mx = fmaxf(mx, fmaxf(f.x,f.y)); }
  #pragma unroll
  for (int o=32;o;o>>=1) mx = fmaxf(mx, __shfl_xor(mx,o));
  __shared__ float sb[4], sb2[4];
  if ((t&63)==0) sb[t>>6]=mx;
  __syncthreads();
  mx = fmaxf(fmaxf(sb[0],sb[1]),fmaxf(sb[2],sb[3]));
  float s=0;
  for (int i=t;i<n2;i+=256){ float2 f = __half22float2(p[i]); s += __expf(f.x-mx)+__expf(f.y-mx); }
  #pragma unroll
  for (int o=32;o;o>>=1) s += __shfl_xor(s,o);
  if ((t&63)==0) sb2[t>>6]=s;
  __syncthreads();
  s = sb2[0]+sb2[1]+sb2[2]+sb2[3];
  if (t==0) stats[row] = make_float2(mx, 1.f/s);
}

// ---------------- row stats for 256-long rows: 16 rows/block, 16 lanes/row ----------------
__global__ __launch_bounds__(256) void stats256_kernel(const __half* __restrict__ logits,
    float2* __restrict__ stats){
  int t = threadIdx.x;
  size_t row = (size_t)blockIdx.x*16 + (t>>4);
  int l16 = t&15;
  const __half2* p = (const __half2*)(logits + row*256);
  float2 f[8];
  #pragma unroll
  for (int i=0;i<8;i++) f[i] = __half22float2(p[l16*8+i]);
  float mx=-1e30f;
  #pragma unroll
  for (int i=0;i<8;i++) mx = fmaxf(mx, fmaxf(f[i].x,f[i].y));
  #pragma unroll
  for (int o=1;o<16;o<<=1) mx = fmaxf(mx, __shfl_xor(mx,o));
  float s=0;
  #pragma unroll
  for (int i=0;i<8;i++) s += __expf(f[i].x-mx)+__expf(f[i].y-mx);
  #pragma unroll
  for (int o=1;o<16;o<<=1) s += __shfl_xor(s,o);
  if (l16==0) stats[row] = make_float2(mx, 1.f/s);
}

// ---------------- out3 partials: softmax(logits3) @ v, K-split by 8 ----------------
__global__ __launch_bounds__(256) void gemm_out3(const __half* __restrict__ Lall,
    const float2* __restrict__ stall, const u16* __restrict__ vall, float* __restrict__ part){
  int bh = blockIdx.z, mt = blockIdx.x, ks = blockIdx.y;
  const __half* L = Lall + (size_t)bh*256*4096 + (size_t)mt*128*4096 + (size_t)ks*512;
  const float2* st = stall + (size_t)bh*256 + mt*128;
  const u16* V = vall + (size_t)bh*4096*64 + (size_t)ks*512*64;
  float* O = part + ((size_t)(bh*8+ks)*256 + (size_t)mt*128)*64;
  __shared__ short As[128*72], Bs[64*72];
  int tid=threadIdx.x, lane=tid&63, w=tid>>6;
  f4 acc[2][4];
  #pragma unroll
  for (int i=0;i<2;i++){
    #pragma unroll
    for (int j=0;j<4;j++) acc[i][j]=0;
  }
  for (int kt=0;kt<8;kt++){
    __syncthreads();
    #pragma unroll
    for (int i=0;i<4;i++){
      int c=i*256+tid, row=c>>3, kg=c&7;
      const __half2* src = (const __half2*)(L + (size_t)row*4096 + kt*64 + kg*8);
      float2 ms = st[row];
      sh8 ov;
      #pragma unroll
      for (int jj=0;jj<4;jj++){
        float2 f = __half22float2(src[jj]);
        ov[2*jj]   = (short)f2bf(__expf(f.x-ms.x)*ms.y);
        ov[2*jj+1] = (short)f2bf(__expf(f.y-ms.x)*ms.y);
      }
      *(sh8*)&As[row*72+kg*8] = ov;
    }
    #pragma unroll
    for (int i=0;i<16;i++){
      int c=i*256+tid, d=c&63, nl=c>>6;
      Bs[d*72+nl] = (short)V[(size_t)(kt*64+nl)*64 + d];
    }
    __syncthreads();
    #pragma unroll
    for (int kc=0;kc<2;kc++){
      sh8 a[2], bq[4];
      #pragma unroll
      for (int fr=0;fr<2;fr++) a[fr]  = *(const sh8*)&As[(w*32+fr*16+(lane&15))*72 + kc*32+((lane>>4)<<3)];
      #pragma unroll
      for (int fc=0;fc<4;fc++) bq[fc] = *(const sh8*)&Bs[(fc*16+(lane&15))*72 + kc*32+((lane>>4)<<3)];
      #pragma unroll
      for (int fr=0;fr<2;fr++){
        #pragma unroll
        for (int fc=0;fc<4;fc++)
          acc[fr][fc] = __builtin_amdgcn_mfma_f32_16x16x32_bf16(a[fr], bq[fc], acc[fr][fc], 0,0,0);
      }
    }
  }
  #pragma unroll
  for (int fr=0;fr<2;fr++){
    #pragma unroll
    for (int fc=0;fc<4;fc++){
      #pragma unroll
      for (int j=0;j<4;j++)
        O[(size_t)(w*32+fr*16+((lane>>4)<<2)+j)*64 + fc*16+(lane&15)] = acc[fr][fc][j];
    }
  }
}

__global__ __launch_bounds__(256) void reduce_o3(const float* __restrict__ part, float* __restrict__ o3){
  int idx = blockIdx.x*256+threadIdx.x;
  int bh = idx>>14, rem = idx & 16383;
  float s=0;
  #pragma unroll
  for (int ks=0;ks<8;ks++) s += part[(((size_t)(bh*8+ks))<<14) + rem];
  o3[idx]=s;
}

// ---------------- Wt[d][m] = (z @ out3)[m][d] bf16, z in hi/lo ----------------
__global__ __launch_bounds__(256) void wt_kernel(const u16* __restrict__ Zhi,
    const u16* __restrict__ Zlo, const float* __restrict__ o3, u16* __restrict__ Wt){
  int bh = blockIdx.x; int m = blockIdx.y*4 + (threadIdx.x>>6); int d = threadIdx.x&63;
  const u16* zh = Zhi + ((size_t)bh*256 + m)*256;
  const u16* zl = Zlo + ((size_t)bh*256 + m)*256;
  const float* op = o3 + (size_t)bh*256*64 + d;
  float accv = 0;
  for (int kk=0;kk<256;kk++) accv += (bf2f(zh[kk])+bf2f(zl[kk]))*op[kk*64];
  Wt[((size_t)bh*64 + d)*256 + m] = f2bf(accv);
}

// ---------------- out1 = softmax(logits1) @ W : (4096x256)@(256x64) per bh ----------------
__global__ __launch_bounds__(256) void gemm_out1(const __half* __restrict__ Lall,
    const float2* __restrict__ stall, const u16* __restrict__ Wtall, float* __restrict__ Oall){
  int bh = blockIdx.z, mt = blockIdx.x;
  const __half* L = Lall + (size_t)bh*4096*256 + (size_t)mt*128*256;
  const float2* st = stall + (size_t)bh*4096 + mt*128;
  const u16* Wt = Wtall + (size_t)bh*64*256;
  float* O = Oall + ((size_t)bh*4096 + (size_t)mt*128)*64;
  __shared__ short As[128*72], Bs[64*72];
  int tid=threadIdx.x, lane=tid&63, w=tid>>6;
  f4 acc[2][4];
  #pragma unroll
  for (int i=0;i<2;i++){
    #pragma unroll
    for (int j=0;j<4;j++) acc[i][j]=0;
  }
  for (int kt=0;kt<4;kt++){
    __syncthreads();
    #pragma unroll
    for (int i=0;i<4;i++){
      int c=i*256+tid, row=c>>3, kg=c&7;
      const __half2* src = (const __half2*)(L + (size_t)row*256 + kt*64 + kg*8);
      float2 ms = st[row];
      sh8 ov;
      #pragma unroll
      for (int jj=0;jj<4;jj++){
        float2 f = __half22float2(src[jj]);
        ov[2*jj]   = (short)f2bf(__expf(f.x-ms.x)*ms.y);
        ov[2*jj+1] = (short)f2bf(__expf(f.y-ms.x)*ms.y);
      }
      *(sh8*)&As[row*72+kg*8] = ov;
    }
    #pragma unroll
    for (int i=0;i<2;i++){
      int c=i*256+tid, row=c>>3, kg=c&7;
      *(sh8*)&Bs[row*72+kg*8] = *(const sh8*)(Wt + (size_t)row*256 + kt*64 + kg*8);
    }
    __syncthreads();
    #pragma unroll
    for (int kc=0;kc<2;kc++){
      sh8 a[2], bq[4];
      #pragma unroll
      for (int fr=0;fr<2;fr++) a[fr]  = *(const sh8*)&As[(w*32+fr*16+(lane&15))*72 + kc*32+((lane>>4)<<3)];
      #pragma unroll
      for (int fc=0;fc<4;fc++) bq[fc] = *(const sh8*)&Bs[(fc*16+(lane&15))*72 + kc*32+((lane>>4)<<3)];
      #pragma unroll
      for (int fr=0;fr<2;fr++){
        #pragma unroll
        for (int fc=0;fc<4;fc++)
          acc[fr][fc] = __builtin_amdgcn_mfma_f32_16x16x32_bf16(a[fr], bq[fc], acc[fr][fc], 0,0,0);
      }
    }
  }
  #pragma unroll
  for (int fr=0;fr<2;fr++){
    #pragma unroll
    for (int fc=0;fc<4;fc++){
      #pragma unroll
      for (int j=0;j<4;j++)
        O[(size_t)(w*32+fr*16+((lane>>4)<<2)+j)*64 + fc*16+(lane&15)] = acc[fr][fc][j];
    }
  }
}

// ---------------- combine: register-window depthwise conv + residual add ----------------
__global__ __launch_bounds__(256) void combine_kernel(const float* __restrict__ out1,
    const u16* __restrict__ v, const float* __restrict__ wres, u16* __restrict__ oc){
  int bh = blockIdx.x; int hh = bh&7, bb = bh>>3;
  int n0 = blockIdx.y*64;
  int tid = threadIdx.x, d = tid&63, sub = tid>>6;
  int nbase = n0 + sub*16;
  const u16* vb = v + ((size_t)bh*4096)*64 + d;
  float w_[33];
  #pragma unroll
  for (int j=0;j<33;j++) w_[j] = wres[hh*33+j];
  float vv[48];
  #pragma unroll
  for (int i=0;i<48;i++){
    int nn = nbase + i - 16;
    vv[i] = (nn>=0 && nn<4096) ? bf2f(vb[(size_t)nn*64]) : 0.f;
  }
  #pragma unroll
  for (int r=0;r<16;r++){
    int n = nbase + r;
    float acc = out1[(((size_t)bh*4096)+n)*64 + d];
    #pragma unroll
    for (int j=0;j<33;j++) acc += w_[j]*vv[r+j];
    oc[((size_t)(bb*4096+n))*512 + hh*64 + d] = f2bf(acc);
  }
}

// ---------------- final: out = x + ocomb @ w_out + b_out ----------------
__global__ __launch_bounds__(256) void gemm_final(const u16* __restrict__ A,
    const u16* __restrict__ Bt, const float* __restrict__ x, const float* __restrict__ bo,
    float* __restrict__ out){
  __shared__ short As[128*72], Bs[128*72];
  int r0 = blockIdx.x*128, c0 = blockIdx.y*128;
  int tid = threadIdx.x, lane = tid&63, w = tid>>6;
  int wr = w>>1, wc = w&1;
  f4 acc[4][4];
  #pragma unroll
  for (int i=0;i<4;i++){
    #pragma unroll
    for (int j=0;j<4;j++) acc[i][j]=0;
  }
  for (int kt=0;kt<8;kt++){
    __syncthreads();
    #pragma unroll
    for (int i=0;i<4;i++){
      int c = i*256+tid, row = c>>3, kg = c&7;
      *(sh8*)&As[row*72+kg*8] = *(const sh8*)(A  + (size_t)(r0+row)*512 + kt*64 + kg*8);
      *(sh8*)&Bs[row*72+kg*8] = *(const sh8*)(Bt + (size_t)(c0+row)*512 + kt*64 + kg*8);
    }
    __syncthreads();
    #pragma unroll
    for (int kc=0;kc<2;kc++){
      sh8 a[4], bq[4];
      #pragma unroll
      for (int fr=0;fr<4;fr++) a[fr]  = *(const sh8*)&As[(wr*64+fr*16+(lane&15))*72 + kc*32 + ((lane>>4)<<3)];
      #pragma unroll
      for (int fc=0;fc<4;fc++) bq[fc] = *(const sh8*)&Bs[(wc*64+fc*16+(lane&15))*72 + kc*32 + ((lane>>4)<<3)];
      #pragma unroll
      for (int fr=0;fr<4;fr++){
        #pragma unroll
        for (int fc=0;fc<4;fc++)
          acc[fr][fc] = __builtin_amdgcn_mfma_f32_16x16x32_bf16(a[fr], bq[fc], acc[fr][fc], 0,0,0);
      }
    }
  }
  #pragma unroll
  for (int fr=0;fr<4;fr++){
    #pragma unroll
    for (int fc=0;fc<4;fc++){
      #pragma unroll
      for (int j=0;j<4;j++){
        int r = r0 + wr*64 + fr*16 + ((lane>>4)<<2) + j;
        int c = c0 + wc*64 + fc*16 + (lane&15);
        out[(size_t)r*512+c] = x[(size_t)r*512+c] + acc[fr][fc][j] + bo[c];
      }
    }
  }
}

extern "C" void kernel_launch(void* const* d_in, const int* in_sizes, int n_in,
                              void* d_out, int out_size, void* d_ws, size_t ws_size,
                              hipStream_t stream){
  const float* x    = (const float*)d_in[0];
  const float* lnw  = (const float*)d_in[1];
  const float* lnb  = (const float*)d_in[2];
  const float* wqkv = (const float*)d_in[3];
  const float* wout = (const float*)d_in[4];
  const float* bout = (const float*)d_in[5];
  const float* wres = (const float*)d_in[6];
  float* out = (float*)d_out;

  char* ws = (char*)d_ws;
  size_t off = 0;
  auto alloc = [&](size_t bytes)->void*{ void* p = ws + off; off += (bytes + 255) & ~(size_t)255; return p; };
  u16* h      = (u16*)alloc((size_t)NT_*512*2);          // aliased later as oc
  u16* wqkvT  = (u16*)alloc((size_t)1536*512*2);
  u16* woutT  = (u16*)alloc((size_t)512*512*2);
  u16* k      = (u16*)alloc((size_t)BH_*4096*64*2);
  u16* v      = (u16*)alloc((size_t)BH_*4096*64*2);
  u16* q      = (u16*)alloc((size_t)BH_*4096*64*2);      // out1 aliases q+part
  float* part = (float*)alloc((size_t)BH_*8*256*64*4);
  u16* ql     = (u16*)alloc((size_t)BH_*256*64*2);
  u16* kl     = (u16*)alloc((size_t)BH_*256*64*2);
  u16* ZaChi  = (u16*)alloc((size_t)BH_*65536*2);        // final z lands here (6 even swaps)
  u16* ZaClo  = (u16*)alloc((size_t)BH_*65536*2);
  __half* logits = (__half*)alloc((size_t)BH_*4096*256*2); // 64 MiB; pinv scratch aliases this
  float2* st3 = (float2*)alloc((size_t)BH_*256*8);
  float2* st1 = (float2*)alloc((size_t)BH_*4096*8);
  float* o3   = (float*)alloc((size_t)BH_*256*64*4);
  u16* Wt     = (u16*)alloc((size_t)BH_*64*256*2);
  float* scal = (float*)alloc(256);
  float* out1 = (float*)q;   // 33.5 MB spans q (16.8) + part (16.8); both dead by then
  u16* oc     = h;           // h dead after qkv gemm

  // pinv scratch carved from the logits region (dead until after pinv loop)
  const size_t C1 = (size_t)BH_*65536;  // elems per component
  u16* base = (u16*)logits;
  u16* Xhi  = base + 0*C1;  u16* Xlo  = base + 1*C1;
  u16* ZaThi= base + 2*C1;  u16* ZaTlo= base + 3*C1;
  u16* ZbChi= base + 4*C1;  u16* ZbClo= base + 5*C1;
  u16* ZbThi= base + 6*C1;  u16* ZbTlo= base + 7*C1;
  u16* T1Chi= base + 8*C1;  u16* T1Clo= base + 9*C1;
  u16* T1Thi= base +10*C1;  u16* T1Tlo= base +11*C1;
  u16* T2Thi= base +12*C1;  u16* T2Tlo= base +13*C1;
  u16* T3Thi= base +14*C1;  u16* T3Tlo= base +15*C1;

  ln_kernel<<<NT_, 256, 0, stream>>>(x, lnw, lnb, h);
  castT_kernel<<<(512*1536+255)/256, 256, 0, stream>>>(wqkv, wqkvT, 512, 1536);
  castT_kernel<<<(512*512+255)/256, 256, 0, stream>>>(wout, woutT, 512, 512);
  gemm_qkv<<<dim3(128,12,1), 256, 0, stream>>>(h, wqkvT, q, k, v);
  landmark_kernel<<<dim3(32,256,1), 64, 0, stream>>>(q, k, ql, kl);
  attn2_kernel<<<dim3(32,16,1), 256, 0, stream>>>(ql, kl, Xhi, Xlo);
  hipMemsetAsync(scal, 0, 8, stream);
  colrow_kernel<<<32, 256, 0, stream>>>(Xhi, Xlo, scal);
  ztinit_kernel<<<dim3(32,4,4), 256, 0, stream>>>(Xhi, Xlo, scal, ZaChi, ZaClo, ZaThi, ZaTlo);

  u16 *zch=ZaChi, *zcl=ZaClo, *zth=ZaThi, *ztl=ZaTlo;
  u16 *wch=ZbChi, *wcl=ZbClo, *wth=ZbThi, *wtl=ZbTlo;
  for (int it=0; it<6; it++){
    // T1 = X @ Z
    pinv_mm<<<dim3(4,4,32),256,0,stream>>>(Xhi,Xlo, zth,ztl, T1Chi,T1Clo, T1Thi,T1Tlo, 0.f, 1.f, 0);
    // T2 = 7*T1 - T1@T1   (store transposed only)
    pinv_mm<<<dim3(4,4,32),256,0,stream>>>(T1Chi,T1Clo, T1Thi,T1Tlo, (u16*)0,(u16*)0, T2Thi,T2Tlo, 7.f, 1.f, 1);
    // T3 = 15*T1 - T1@T2  (store transposed only)
    pinv_mm<<<dim3(4,4,32),256,0,stream>>>(T1Chi,T1Clo, T2Thi,T2Tlo, (u16*)0,(u16*)0, T3Thi,T3Tlo, 15.f, 1.f, 1);
    // Z' = 0.25*(13*Z - Z@T3)  (store both forms)
    pinv_mm<<<dim3(4,4,32),256,0,stream>>>(zch,zcl, T3Thi,T3Tlo, wch,wcl, wth,wtl, 13.f, 0.25f, 1);
    u16* t;
    t=zch; zch=wch; wch=t;  t=zcl; zcl=wcl; wcl=t;
    t=zth; zth=wth; wth=t;  t=ztl; ztl=wtl; wtl=t;
  }
  // zch/zcl == ZaChi/ZaClo hold the final pinv (outside the logits alias region)

  gemm_logits<<<dim3(2,32,32),256,0,stream>>>(ql, k, logits, 4096,
      (size_t)256*64, (size_t)4096*64, (size_t)256*4096);
  stats_kernel<<<BH_*256, 256, 0, stream>>>(logits, st3, 4096);
  gemm_out3<<<dim3(2,8,32),256,0,stream>>>(logits, st3, v, part);
  reduce_o3<<<2048, 256, 0, stream>>>(part, o3);
  wt_kernel<<<dim3(32,64,1),256,0,stream>>>(zch, zcl, o3, Wt);
  gemm_logits<<<dim3(32,2,32),256,0,stream>>>(q, kl, logits, 256,
      (size_t)4096*64, (size_t)256*64, (size_t)4096*256);
  stats256_kernel<<<8192, 256, 0, stream>>>(logits, st1);
  gemm_out1<<<dim3(32,1,32),256,0,stream>>>(logits, st1, Wt, out1);
  combine_kernel<<<dim3(32,64,1),256,0,stream>>>(out1, v, wres, oc);
  gemm_final<<<dim3(128,4,1),256,0,stream>>>(oc, woutT, x, bout, out);
}